// Round 4
// baseline (328.840 us; speedup 1.0000x reference)
//
#include <hip/hip_runtime.h>

#define D_DIRS 4
#define BB 2
#define CC 96
#define LL 4096
#define PP 192
#define TWOP 384
#define NN 16
#define DTR 6
#define NPROJ 38
#define NCH 256
#define CLEN 16
#define SEQT 24576   // 8 db * 192 p * 16 n

typedef __bf16 bf16x8 __attribute__((ext_vector_type(8)));
typedef float f32x4 __attribute__((ext_vector_type(4)));

__device__ __forceinline__ float fast_softplus(float v) {
    return fmaxf(v, 0.0f) + __logf(1.0f + __expf(-fabsf(v)));
}

// time index t (within a direction's sequence) -> flat pixel offset h*64+w in x1
__device__ __forceinline__ int pixoff(int d, int t) {
    int tt = (d & 1) ? (LL - 1 - t) : t;
    if (d < 2) return tt;                      // seq_h: l = h*W + w
    return ((tt & 63) << 6) | (tt >> 6);       // seq_w: l = w*H + h -> pixel h*W+w
}

// ---------------- weight prep: fp32 -> padded bf16 images ----------------
__global__ void k_prep(const float* __restrict__ W_in, const float* __restrict__ W_x,
                       const float* __restrict__ W_out, __bf16* __restrict__ wbin,
                       __bf16* __restrict__ wbx, __bf16* __restrict__ wbout)
{
    int i = blockIdx.x * 256 + threadIdx.x;
    const int n0 = 4 * 384 * 104, n1 = 4 * 48 * 200, n2 = 4 * 96 * 200;
    if (i < n0) {
        int c = i % 104, jd = i / 104;          // jd = d*384 + j
        wbin[i] = (c < 96) ? (__bf16)W_in[jd * 96 + c] : (__bf16)0.0f;
    } else if (i < n0 + n1) {
        int k = i - n0;
        int c = k % 200, jd = k / 200;          // jd = d*48 + j
        int d = jd / 48, j = jd - d * 48;
        float v = (j < 38 && c < 192) ? W_x[(d * 38 + j) * 192 + c] : 0.0f;
        wbx[k] = (__bf16)v;
    } else if (i < n0 + n1 + n2) {
        int k = i - n0 - n1;
        int c = k % 200, jd = k / 200;          // jd = d*96 + cout
        float v = (c < 192) ? W_out[jd * 192 + c] : 0.0f;
        wbout[k] = (__bf16)v;
    }
}

// ---------------- input GEMM (MFMA): x-half -> xz_x (f32), z-half -> zb (bf16) ----------------
__global__ __launch_bounds__(256) void k_gemm_in(
    const float* __restrict__ x1, const __bf16* __restrict__ wbin,
    float* __restrict__ xz_x, __bf16* __restrict__ zb)
{
    __shared__ __align__(16) __bf16 As[64 * 104];
    __shared__ __align__(16) __bf16 Bs[64 * 104];
    const int db = blockIdx.z;
    const int d = db >> 1, b = db & 1;
    const int t0 = blockIdx.x * 64;
    const int j0 = blockIdx.y * 64;
    const int tid = threadIdx.x;

    for (int i = tid; i < 64 * 96; i += 256) {
        int t = i & 63, c = i >> 6;
        int pix = pixoff(d, t0 + t);
        As[t * 104 + c] = (__bf16)x1[(b * CC + c) * LL + pix];
    }
    {
        const uint4* bsrc = reinterpret_cast<const uint4*>(wbin + (d * 384 + j0) * 104);
        uint4* bdst = reinterpret_cast<uint4*>(Bs);
        for (int i = tid; i < 832; i += 256) bdst[i] = bsrc[i];
    }
    __syncthreads();

    const int lane = tid & 63;
    const int w = tid >> 6;
    const int wm = (w >> 1) * 32, wn = (w & 1) * 32;
    const int lr = lane & 15, lk = (lane >> 4) * 8;
    const int orow = (lane >> 4) * 4;

    f32x4 acc[2][2] = {{{0.f,0.f,0.f,0.f},{0.f,0.f,0.f,0.f}},
                       {{0.f,0.f,0.f,0.f},{0.f,0.f,0.f,0.f}}};
#pragma unroll
    for (int ks = 0; ks < 96; ks += 32) {
        bf16x8 a0 = *(const bf16x8*)&As[(wm + lr) * 104 + ks + lk];
        bf16x8 a1 = *(const bf16x8*)&As[(wm + 16 + lr) * 104 + ks + lk];
        bf16x8 b0 = *(const bf16x8*)&Bs[(wn + lr) * 104 + ks + lk];
        bf16x8 b1 = *(const bf16x8*)&Bs[(wn + 16 + lr) * 104 + ks + lk];
        acc[0][0] = __builtin_amdgcn_mfma_f32_16x16x32_bf16(a0, b0, acc[0][0], 0, 0, 0);
        acc[0][1] = __builtin_amdgcn_mfma_f32_16x16x32_bf16(a0, b1, acc[0][1], 0, 0, 0);
        acc[1][0] = __builtin_amdgcn_mfma_f32_16x16x32_bf16(a1, b0, acc[1][0], 0, 0, 0);
        acc[1][1] = __builtin_amdgcn_mfma_f32_16x16x32_bf16(a1, b1, acc[1][1], 0, 0, 0);
    }
#pragma unroll
    for (int mi = 0; mi < 2; ++mi)
#pragma unroll
        for (int ni = 0; ni < 2; ++ni) {
            int jcol = j0 + wn + ni * 16 + lr;
            long mbase = (long)(db * LL + t0 + wm + mi * 16 + orow);
            if (jcol < PP) {
#pragma unroll
                for (int r = 0; r < 4; ++r) xz_x[(mbase + r) * PP + jcol] = acc[mi][ni][r];
            } else {
#pragma unroll
                for (int r = 0; r < 4; ++r) zb[(mbase + r) * PP + jcol - PP] = (__bf16)acc[mi][ni][r];
            }
        }
}

// ---------------- proj GEMM (MFMA): proj[m][j] = sum_k xbuf[m][k]*W_x[d][j][k], J=38 ----------------
__global__ __launch_bounds__(256) void k_gemm_proj(
    const float* __restrict__ Abuf, const __bf16* __restrict__ wbx, float* __restrict__ proj)
{
    __shared__ __align__(16) __bf16 As[64 * 200];
    __shared__ __align__(16) __bf16 Bs[48 * 200];
    const int m0 = blockIdx.x * 64;
    const int d = m0 >> 13;
    const int tid = threadIdx.x;

    for (int i = tid; i < 64 * 48; i += 256) {
        int t = i / 48, c4 = (i - t * 48) * 4;
        float4 v = *(const float4*)&Abuf[(long)(m0 + t) * PP + c4];
        union { __bf16 h[4]; uint2 u; } pk;
        pk.h[0] = (__bf16)v.x; pk.h[1] = (__bf16)v.y; pk.h[2] = (__bf16)v.z; pk.h[3] = (__bf16)v.w;
        *(uint2*)&As[t * 200 + c4] = pk.u;
    }
    {
        const uint4* bsrc = reinterpret_cast<const uint4*>(wbx + d * 48 * 200);
        uint4* bdst = reinterpret_cast<uint4*>(Bs);
        for (int i = tid; i < 1200; i += 256) bdst[i] = bsrc[i];
    }
    __syncthreads();

    const int lane = tid & 63;
    const int w = tid >> 6;
    const int lr = lane & 15, lk = (lane >> 4) * 8;
    const int orow = (lane >> 4) * 4;

    f32x4 acc[3] = {{0.f,0.f,0.f,0.f},{0.f,0.f,0.f,0.f},{0.f,0.f,0.f,0.f}};
#pragma unroll
    for (int ks = 0; ks < 192; ks += 32) {
        bf16x8 a = *(const bf16x8*)&As[(w * 16 + lr) * 200 + ks + lk];
#pragma unroll
        for (int ni = 0; ni < 3; ++ni) {
            bf16x8 bfr = *(const bf16x8*)&Bs[(ni * 16 + lr) * 200 + ks + lk];
            acc[ni] = __builtin_amdgcn_mfma_f32_16x16x32_bf16(a, bfr, acc[ni], 0, 0, 0);
        }
    }
#pragma unroll
    for (int ni = 0; ni < 3; ++ni) {
        int j = ni * 16 + lr;
        if (j < NPROJ) {
#pragma unroll
            for (int r = 0; r < 4; ++r) {
                int m = m0 + w * 16 + orow + r;
                proj[(long)m * NPROJ + j] = acc[ni][r];
            }
        }
    }
}

// ---------------- out GEMM (MFMA): yo[m][c] = sum_p ys[m][p]*W_out[d][c][p], J=96 ----------------
__global__ __launch_bounds__(256) void k_gemm_out(
    const float* __restrict__ Abuf, const __bf16* __restrict__ wbout, float* __restrict__ yo)
{
    __shared__ __align__(16) __bf16 As[64 * 200];
    __shared__ __align__(16) __bf16 Bs[96 * 200];
    const int m0 = blockIdx.x * 64;
    const int d = m0 >> 13;
    const int tid = threadIdx.x;

    for (int i = tid; i < 64 * 48; i += 256) {
        int t = i / 48, c4 = (i - t * 48) * 4;
        float4 v = *(const float4*)&Abuf[(long)(m0 + t) * PP + c4];
        union { __bf16 h[4]; uint2 u; } pk;
        pk.h[0] = (__bf16)v.x; pk.h[1] = (__bf16)v.y; pk.h[2] = (__bf16)v.z; pk.h[3] = (__bf16)v.w;
        *(uint2*)&As[t * 200 + c4] = pk.u;
    }
    {
        const uint4* bsrc = reinterpret_cast<const uint4*>(wbout + d * 96 * 200);
        uint4* bdst = reinterpret_cast<uint4*>(Bs);
        for (int i = tid; i < 2400; i += 256) bdst[i] = bsrc[i];
    }
    __syncthreads();

    const int lane = tid & 63;
    const int w = tid >> 6;
    const int wm = (w >> 1) * 32, wn = (w & 1) * 48;
    const int lr = lane & 15, lk = (lane >> 4) * 8;
    const int orow = (lane >> 4) * 4;

    f32x4 acc[2][3] = {};
#pragma unroll
    for (int ks = 0; ks < 192; ks += 32) {
        bf16x8 a0 = *(const bf16x8*)&As[(wm + lr) * 200 + ks + lk];
        bf16x8 a1 = *(const bf16x8*)&As[(wm + 16 + lr) * 200 + ks + lk];
#pragma unroll
        for (int ni = 0; ni < 3; ++ni) {
            bf16x8 bfr = *(const bf16x8*)&Bs[(wn + ni * 16 + lr) * 200 + ks + lk];
            acc[0][ni] = __builtin_amdgcn_mfma_f32_16x16x32_bf16(a0, bfr, acc[0][ni], 0, 0, 0);
            acc[1][ni] = __builtin_amdgcn_mfma_f32_16x16x32_bf16(a1, bfr, acc[1][ni], 0, 0, 0);
        }
    }
#pragma unroll
    for (int mi = 0; mi < 2; ++mi)
#pragma unroll
        for (int ni = 0; ni < 3; ++ni) {
#pragma unroll
            for (int r = 0; r < 4; ++r) {
                int m = m0 + wm + mi * 16 + orow + r;
                yo[(long)m * CC + wn + ni * 16 + lr] = acc[mi][ni][r];
            }
        }
}

// ---------------- depthwise causal conv (k=4) + bias + SiLU ----------------
__global__ void k_conv(const float* __restrict__ xz_x, const float* __restrict__ conv_w,
                       const float* __restrict__ conv_b, float* __restrict__ xbuf)
{
    int idx = blockIdx.x * blockDim.x + threadIdx.x;
    const int total = D_DIRS * BB * LL * PP;
    for (; idx < total; idx += gridDim.x * blockDim.x) {
        int p = idx % PP;
        int m = idx / PP;
        int t = m & (LL - 1);
        int d = m >> 13;
        float acc = conv_b[d * PP + p];
        const float* wp = conv_w + (d * PP + p) * 4;
#pragma unroll
        for (int k = 0; k < 4; ++k) {
            int tt = t - 3 + k;
            if (tt >= 0) acc += wp[k] * xz_x[(long)(m - 3 + k) * PP + p];
        }
        xbuf[(long)m * PP + p] = acc / (1.0f + __expf(-acc));
    }
}

// ---------------- scan pass 1: 1 thread per (p,chunk,db), 16 states in regs ----------------
__global__ __launch_bounds__(192, 4) void k_pass1(
    const float* __restrict__ xbuf, const float* __restrict__ proj,
    const float* __restrict__ A_log, const float* __restrict__ W_dt,
    const float* __restrict__ b_dt,
    float* __restrict__ cb_pa, float* __restrict__ cb_h)
{
    __shared__ __align__(16) float pl[CLEN * 40];  // 0..5 dtproj, 6..7 zero, 8..23 B, 24..39 C
    const int tid = threadIdx.x;      // = p
    const int chunk = blockIdx.x;
    const int db = blockIdx.y;
    const int d = db >> 1;
    const int m0 = db * LL + chunk * CLEN;

    const float* pr = proj + (long)m0 * NPROJ;
    for (int i = tid; i < CLEN * NPROJ; i += 192) {
        int r = i / NPROJ, c = i - r * NPROJ;
        int col = (c < 6) ? c : c + 2;
        pl[r * 40 + col] = pr[i];
    }
    if (tid < CLEN) { pl[tid * 40 + 6] = 0.f; pl[tid * 40 + 7] = 0.f; }

    const int p = tid;
    float xv[CLEN];
    const float* xp = xbuf + (long)m0 * PP + p;
#pragma unroll
    for (int s = 0; s < CLEN; ++s) xv[s] = xp[s * PP];

    float A[16];
    const float* al = A_log + (d * PP + p) * NN;
#pragma unroll
    for (int n = 0; n < 16; ++n) A[n] = -__expf(al[n]);
    float w[6];
    const float* wd = W_dt + (d * PP + p) * DTR;
#pragma unroll
    for (int r = 0; r < 6; ++r) w[r] = wd[r];
    const float bdt = b_dt[d * PP + p];
    float h[16], pa[16];
#pragma unroll
    for (int n = 0; n < 16; ++n) { h[n] = 0.f; pa[n] = 1.f; }
    __syncthreads();

#pragma unroll
    for (int s = 0; s < CLEN; ++s) {
        const float* row = pl + s * 40;
        float4 d0 = *(const float4*)(row);
        float4 d1 = *(const float4*)(row + 4);
        float v = bdt + d0.x*w[0] + d0.y*w[1] + d0.z*w[2] + d0.w*w[3] + d1.x*w[4] + d1.y*w[5];
        float dtv = fast_softplus(v);
        float dtx = dtv * xv[s];
        const float4* B4 = reinterpret_cast<const float4*>(row + 8);
#pragma unroll
        for (int q = 0; q < 4; ++q) {
            float4 Bv = B4[q];
            float dA;
            dA = __expf(dtv * A[4*q+0]); h[4*q+0] = dA*h[4*q+0] + dtx*Bv.x; pa[4*q+0] *= dA;
            dA = __expf(dtv * A[4*q+1]); h[4*q+1] = dA*h[4*q+1] + dtx*Bv.y; pa[4*q+1] *= dA;
            dA = __expf(dtv * A[4*q+2]); h[4*q+2] = dA*h[4*q+2] + dtx*Bv.z; pa[4*q+2] *= dA;
            dA = __expf(dtv * A[4*q+3]); h[4*q+3] = dA*h[4*q+3] + dtx*Bv.w; pa[4*q+3] *= dA;
        }
    }
    const int seq = db * (PP * NN) + p * NN;
    float4* pao = reinterpret_cast<float4*>(cb_pa + (long)chunk * SEQT + seq);
    float4* ho  = reinterpret_cast<float4*>(cb_h  + (long)chunk * SEQT + seq);
#pragma unroll
    for (int q = 0; q < 4; ++q) {
        pao[q] = make_float4(pa[4*q], pa[4*q+1], pa[4*q+2], pa[4*q+3]);
        ho[q]  = make_float4(h[4*q],  h[4*q+1],  h[4*q+2],  h[4*q+3]);
    }
}

// ---------------- serial scan over chunks -> initial states ----------------
__global__ void k_chunkscan(const float* __restrict__ cb_pa, float* __restrict__ cb_h)
{
    int seq = blockIdx.x * 256 + threadIdx.x;   // 0..24575
    float run = 0.0f;
    for (int c = 0; c < NCH; ++c) {
        long o = (long)c * SEQT + seq;
        float pav = cb_pa[o];
        float hv = cb_h[o];
        cb_h[o] = run;
        run = pav * run + hv;
    }
}

// ---------------- scan pass 2: emit ys = (sum_n h*C + x*Dp) * silu(z) ----------------
__global__ __launch_bounds__(192, 4) void k_pass2(
    const float* xbuf_in, const float* __restrict__ proj,
    const float* __restrict__ A_log, const float* __restrict__ W_dt,
    const float* __restrict__ b_dt, const float* __restrict__ Dp,
    const __bf16* __restrict__ zb, const float* __restrict__ cb_h,
    float* ys)   // ys aliases xbuf_in: read-before-write per thread/column
{
    __shared__ __align__(16) float pl[CLEN * 40];
    const int tid = threadIdx.x;
    const int chunk = blockIdx.x;
    const int db = blockIdx.y;
    const int d = db >> 1;
    const int m0 = db * LL + chunk * CLEN;

    const float* pr = proj + (long)m0 * NPROJ;
    for (int i = tid; i < CLEN * NPROJ; i += 192) {
        int r = i / NPROJ, c = i - r * NPROJ;
        int col = (c < 6) ? c : c + 2;
        pl[r * 40 + col] = pr[i];
    }
    if (tid < CLEN) { pl[tid * 40 + 6] = 0.f; pl[tid * 40 + 7] = 0.f; }

    const int p = tid;
    float xv[CLEN], zv[CLEN];
    const float* xp = xbuf_in + (long)m0 * PP + p;
    const __bf16* zp = zb + (long)m0 * PP + p;
#pragma unroll
    for (int s = 0; s < CLEN; ++s) xv[s] = xp[s * PP];
#pragma unroll
    for (int s = 0; s < CLEN; ++s) zv[s] = (float)zp[s * PP];

    float A[16];
    const float* al = A_log + (d * PP + p) * NN;
#pragma unroll
    for (int n = 0; n < 16; ++n) A[n] = -__expf(al[n]);
    float w[6];
    const float* wd = W_dt + (d * PP + p) * DTR;
#pragma unroll
    for (int r = 0; r < 6; ++r) w[r] = wd[r];
    const float bdt = b_dt[d * PP + p];
    const float Dv = Dp[d * PP + p];

    float h[16];
    const int seq = db * (PP * NN) + p * NN;
    const float4* hi = reinterpret_cast<const float4*>(cb_h + (long)chunk * SEQT + seq);
#pragma unroll
    for (int q = 0; q < 4; ++q) {
        float4 hv = hi[q];
        h[4*q] = hv.x; h[4*q+1] = hv.y; h[4*q+2] = hv.z; h[4*q+3] = hv.w;
    }
    __syncthreads();

    float* yp = ys + (long)m0 * PP + p;
#pragma unroll
    for (int s = 0; s < CLEN; ++s) {
        const float* row = pl + s * 40;
        float4 d0 = *(const float4*)(row);
        float4 d1 = *(const float4*)(row + 4);
        float v = bdt + d0.x*w[0] + d0.y*w[1] + d0.z*w[2] + d0.w*w[3] + d1.x*w[4] + d1.y*w[5];
        float dtv = fast_softplus(v);
        float dtx = dtv * xv[s];
        const float4* B4 = reinterpret_cast<const float4*>(row + 8);
        const float4* C4 = reinterpret_cast<const float4*>(row + 24);
        float y = 0.0f;
#pragma unroll
        for (int q = 0; q < 4; ++q) {
            float4 Bv = B4[q];
            float4 Cv = C4[q];
            float dA;
            dA = __expf(dtv * A[4*q+0]); h[4*q+0] = dA*h[4*q+0] + dtx*Bv.x; y += h[4*q+0]*Cv.x;
            dA = __expf(dtv * A[4*q+1]); h[4*q+1] = dA*h[4*q+1] + dtx*Bv.y; y += h[4*q+1]*Cv.y;
            dA = __expf(dtv * A[4*q+2]); h[4*q+2] = dA*h[4*q+2] + dtx*Bv.z; y += h[4*q+2]*Cv.z;
            dA = __expf(dtv * A[4*q+3]); h[4*q+3] = dA*h[4*q+3] + dtx*Bv.w; y += h[4*q+3]*Cv.w;
        }
        float zvv = zv[s];
        yp[s * PP] = (y + xv[s] * Dv) * (zvv / (1.0f + __expf(-zvv)));
    }
}

// ---------------- final combine: out = x2 + sum of 4 directional outputs ----------------
__global__ void k_final(const float* __restrict__ x2, const float* __restrict__ yo,
                        float* __restrict__ out)
{
    int idx = blockIdx.x * blockDim.x + threadIdx.x;
    const int total = BB * CC * LL;
    for (; idx < total; idx += gridDim.x * blockDim.x) {
        int w = idx & 63;
        int h = (idx >> 6) & 63;
        int c = (idx >> 12) % CC;
        int b = idx / (CC * LL);
        int lh = (h << 6) | w;
        int lw = (w << 6) | h;
        long m0 = (long)(0 * BB + b) * LL + lh;
        long m1 = (long)(1 * BB + b) * LL + (LL - 1 - lh);
        long m2 = (long)(2 * BB + b) * LL + lw;
        long m3 = (long)(3 * BB + b) * LL + (LL - 1 - lw);
        out[idx] = x2[idx] + yo[m0 * CC + c] + yo[m1 * CC + c] + yo[m2 * CC + c] + yo[m3 * CC + c];
    }
}

extern "C" void kernel_launch(void* const* d_in, const int* in_sizes, int n_in,
                              void* d_out, int out_size, void* d_ws, size_t ws_size,
                              hipStream_t stream)
{
    const float* x1     = (const float*)d_in[0];
    const float* x2     = (const float*)d_in[1];
    const float* W_in   = (const float*)d_in[2];
    const float* conv_w = (const float*)d_in[3];
    const float* conv_b = (const float*)d_in[4];
    const float* W_x    = (const float*)d_in[5];
    const float* W_dt   = (const float*)d_in[6];
    const float* b_dt   = (const float*)d_in[7];
    const float* A_log  = (const float*)d_in[8];
    const float* Dp     = (const float*)d_in[9];
    const float* W_out  = (const float*)d_in[10];
    float* out = (float*)d_out;
    float* ws  = (float*)d_ws;

    // workspace layout (float offsets), total ~29.70M floats = 118.8 MB
    float*  xz_x  = ws;                          // 6,291,456
    __bf16* zb    = (__bf16*)(ws + 6291456);     // 6,291,456 bf16 = 3,145,728 f
    float*  xbuf  = ws + 9437184;                // 6,291,456  (reused in-place as ys)
    float*  proj  = ws + 15728640;               // 1,245,184
    float*  cb_pa = ws + 16973824;               // 6,291,456  (yo aliases after chunkscan)
    float*  cb_h  = ws + 23265280;               // 6,291,456
    __bf16* wbin  = (__bf16*)(ws + 29556736);    // 159,744 bf16
    __bf16* wbx   = (__bf16*)(ws + 29636608);    // 38,400 bf16
    __bf16* wbout = (__bf16*)(ws + 29655808);    // 76,800 bf16
    float* ys = xbuf;
    float* yo = cb_pa;   // dead after k_chunkscan

    k_prep<<<dim3(1074), 256, 0, stream>>>(W_in, W_x, W_out, wbin, wbx, wbout);
    k_gemm_in<<<dim3(64, 6, 8), 256, 0, stream>>>(x1, wbin, xz_x, zb);
    k_conv<<<dim3(6144), 256, 0, stream>>>(xz_x, conv_w, conv_b, xbuf);
    k_gemm_proj<<<dim3(512), 256, 0, stream>>>(xbuf, wbx, proj);
    k_pass1<<<dim3(NCH, 8), 192, 0, stream>>>(xbuf, proj, A_log, W_dt, b_dt, cb_pa, cb_h);
    k_chunkscan<<<dim3(SEQT / 256), 256, 0, stream>>>(cb_pa, cb_h);
    k_pass2<<<dim3(NCH, 8), 192, 0, stream>>>(xbuf, proj, A_log, W_dt, b_dt, Dp, zb, cb_h, ys);
    k_gemm_out<<<dim3(512), 256, 0, stream>>>(ys, wbout, yo);
    k_final<<<dim3(3072), 256, 0, stream>>>(x2, yo, out);
}

// Round 5
// 237.459 us; speedup vs baseline: 1.3848x; 1.3848x over previous
//
#include <hip/hip_runtime.h>

#define D_DIRS 4
#define BB 2
#define CC 96
#define LL 4096
#define PP 192
#define TWOP 384
#define NN 16
#define DTR 6
#define NPROJ 38
#define NCH 256
#define CLEN 16
#define SEQT 24576   // 8 db * 192 p * 16 n

typedef __bf16 bf16x8 __attribute__((ext_vector_type(8)));
typedef float f32x4 __attribute__((ext_vector_type(4)));

__device__ __forceinline__ float fast_softplus(float v) {
    return fmaxf(v, 0.0f) + __logf(1.0f + __expf(-fabsf(v)));
}

// time index t (within a direction's sequence) -> flat pixel offset h*64+w in x1
__device__ __forceinline__ int pixoff(int d, int t) {
    int tt = (d & 1) ? (LL - 1 - t) : t;
    if (d < 2) return tt;                      // seq_h: l = h*W + w
    return ((tt & 63) << 6) | (tt >> 6);       // seq_w: l = w*H + h -> pixel h*W+w
}

// ---------------- weight prep: fp32 -> padded bf16 images ----------------
__global__ void k_prep(const float* __restrict__ W_in, const float* __restrict__ W_x,
                       const float* __restrict__ W_out, __bf16* __restrict__ wbin,
                       __bf16* __restrict__ wbx, __bf16* __restrict__ wbout)
{
    int i = blockIdx.x * 256 + threadIdx.x;
    const int n0 = 4 * 384 * 104, n1 = 4 * 48 * 200, n2 = 4 * 96 * 200;
    if (i < n0) {
        int c = i % 104, jd = i / 104;          // jd = d*384 + j
        wbin[i] = (c < 96) ? (__bf16)W_in[jd * 96 + c] : (__bf16)0.0f;
    } else if (i < n0 + n1) {
        int k = i - n0;
        int c = k % 200, jd = k / 200;          // jd = d*48 + j
        int d = jd / 48, j = jd - d * 48;
        float v = (j < 38 && c < 192) ? W_x[(d * 38 + j) * 192 + c] : 0.0f;
        wbx[k] = (__bf16)v;
    } else if (i < n0 + n1 + n2) {
        int k = i - n0 - n1;
        int c = k % 200, jd = k / 200;          // jd = d*96 + cout
        float v = (c < 192) ? W_out[jd * 192 + c] : 0.0f;
        wbout[k] = (__bf16)v;
    }
}

// ---------------- input GEMM (MFMA): x-half -> xz_x (f32), z-half -> zb (bf16) ----------------
__global__ __launch_bounds__(256) void k_gemm_in(
    const float* __restrict__ x1, const __bf16* __restrict__ wbin,
    float* __restrict__ xz_x, __bf16* __restrict__ zb)
{
    __shared__ __align__(16) __bf16 As[64 * 104];
    __shared__ __align__(16) __bf16 Bs[64 * 104];
    const int db = blockIdx.z;
    const int d = db >> 1, b = db & 1;
    const int t0 = blockIdx.x * 64;
    const int j0 = blockIdx.y * 64;
    const int tid = threadIdx.x;

    for (int i = tid; i < 64 * 96; i += 256) {
        int t = i & 63, c = i >> 6;
        int pix = pixoff(d, t0 + t);
        As[t * 104 + c] = (__bf16)x1[(b * CC + c) * LL + pix];
    }
    {
        const uint4* bsrc = reinterpret_cast<const uint4*>(wbin + (d * 384 + j0) * 104);
        uint4* bdst = reinterpret_cast<uint4*>(Bs);
        for (int i = tid; i < 832; i += 256) bdst[i] = bsrc[i];
    }
    __syncthreads();

    const int lane = tid & 63;
    const int w = tid >> 6;
    const int wm = (w >> 1) * 32, wn = (w & 1) * 32;
    const int lr = lane & 15, lk = (lane >> 4) * 8;
    const int orow = (lane >> 4) * 4;

    f32x4 acc[2][2] = {{{0.f,0.f,0.f,0.f},{0.f,0.f,0.f,0.f}},
                       {{0.f,0.f,0.f,0.f},{0.f,0.f,0.f,0.f}}};
#pragma unroll
    for (int ks = 0; ks < 96; ks += 32) {
        bf16x8 a0 = *(const bf16x8*)&As[(wm + lr) * 104 + ks + lk];
        bf16x8 a1 = *(const bf16x8*)&As[(wm + 16 + lr) * 104 + ks + lk];
        bf16x8 b0 = *(const bf16x8*)&Bs[(wn + lr) * 104 + ks + lk];
        bf16x8 b1 = *(const bf16x8*)&Bs[(wn + 16 + lr) * 104 + ks + lk];
        acc[0][0] = __builtin_amdgcn_mfma_f32_16x16x32_bf16(a0, b0, acc[0][0], 0, 0, 0);
        acc[0][1] = __builtin_amdgcn_mfma_f32_16x16x32_bf16(a0, b1, acc[0][1], 0, 0, 0);
        acc[1][0] = __builtin_amdgcn_mfma_f32_16x16x32_bf16(a1, b0, acc[1][0], 0, 0, 0);
        acc[1][1] = __builtin_amdgcn_mfma_f32_16x16x32_bf16(a1, b1, acc[1][1], 0, 0, 0);
    }
#pragma unroll
    for (int mi = 0; mi < 2; ++mi)
#pragma unroll
        for (int ni = 0; ni < 2; ++ni) {
            int jcol = j0 + wn + ni * 16 + lr;
            long mbase = (long)(db * LL + t0 + wm + mi * 16 + orow);
            if (jcol < PP) {
#pragma unroll
                for (int r = 0; r < 4; ++r) xz_x[(mbase + r) * PP + jcol] = acc[mi][ni][r];
            } else {
#pragma unroll
                for (int r = 0; r < 4; ++r) zb[(mbase + r) * PP + jcol - PP] = (__bf16)acc[mi][ni][r];
            }
        }
}

// ---------------- proj GEMM (MFMA): proj[m][j] = sum_k xbuf[m][k]*W_x[d][j][k], J=38 ----------------
__global__ __launch_bounds__(256) void k_gemm_proj(
    const float* __restrict__ Abuf, const __bf16* __restrict__ wbx, float* __restrict__ proj)
{
    __shared__ __align__(16) __bf16 As[64 * 200];
    __shared__ __align__(16) __bf16 Bs[48 * 200];
    const int m0 = blockIdx.x * 64;
    const int d = m0 >> 13;
    const int tid = threadIdx.x;

    for (int i = tid; i < 64 * 48; i += 256) {
        int t = i / 48, c4 = (i - t * 48) * 4;
        float4 v = *(const float4*)&Abuf[(long)(m0 + t) * PP + c4];
        union { __bf16 h[4]; uint2 u; } pk;
        pk.h[0] = (__bf16)v.x; pk.h[1] = (__bf16)v.y; pk.h[2] = (__bf16)v.z; pk.h[3] = (__bf16)v.w;
        *(uint2*)&As[t * 200 + c4] = pk.u;
    }
    {
        const uint4* bsrc = reinterpret_cast<const uint4*>(wbx + d * 48 * 200);
        uint4* bdst = reinterpret_cast<uint4*>(Bs);
        for (int i = tid; i < 1200; i += 256) bdst[i] = bsrc[i];
    }
    __syncthreads();

    const int lane = tid & 63;
    const int w = tid >> 6;
    const int lr = lane & 15, lk = (lane >> 4) * 8;
    const int orow = (lane >> 4) * 4;

    f32x4 acc[3] = {{0.f,0.f,0.f,0.f},{0.f,0.f,0.f,0.f},{0.f,0.f,0.f,0.f}};
#pragma unroll
    for (int ks = 0; ks < 192; ks += 32) {
        bf16x8 a = *(const bf16x8*)&As[(w * 16 + lr) * 200 + ks + lk];
#pragma unroll
        for (int ni = 0; ni < 3; ++ni) {
            bf16x8 bfr = *(const bf16x8*)&Bs[(ni * 16 + lr) * 200 + ks + lk];
            acc[ni] = __builtin_amdgcn_mfma_f32_16x16x32_bf16(a, bfr, acc[ni], 0, 0, 0);
        }
    }
#pragma unroll
    for (int ni = 0; ni < 3; ++ni) {
        int j = ni * 16 + lr;
        if (j < NPROJ) {
#pragma unroll
            for (int r = 0; r < 4; ++r) {
                int m = m0 + w * 16 + orow + r;
                proj[(long)m * NPROJ + j] = acc[ni][r];
            }
        }
    }
}

// ---------------- out GEMM (MFMA): yo[m][c] = sum_p ys[m][p]*W_out[d][c][p], J=96 ----------------
__global__ __launch_bounds__(256) void k_gemm_out(
    const float* __restrict__ Abuf, const __bf16* __restrict__ wbout, float* __restrict__ yo)
{
    __shared__ __align__(16) __bf16 As[64 * 200];
    __shared__ __align__(16) __bf16 Bs[96 * 200];
    const int m0 = blockIdx.x * 64;
    const int d = m0 >> 13;
    const int tid = threadIdx.x;

    for (int i = tid; i < 64 * 48; i += 256) {
        int t = i / 48, c4 = (i - t * 48) * 4;
        float4 v = *(const float4*)&Abuf[(long)(m0 + t) * PP + c4];
        union { __bf16 h[4]; uint2 u; } pk;
        pk.h[0] = (__bf16)v.x; pk.h[1] = (__bf16)v.y; pk.h[2] = (__bf16)v.z; pk.h[3] = (__bf16)v.w;
        *(uint2*)&As[t * 200 + c4] = pk.u;
    }
    {
        const uint4* bsrc = reinterpret_cast<const uint4*>(wbout + d * 96 * 200);
        uint4* bdst = reinterpret_cast<uint4*>(Bs);
        for (int i = tid; i < 2400; i += 256) bdst[i] = bsrc[i];
    }
    __syncthreads();

    const int lane = tid & 63;
    const int w = tid >> 6;
    const int wm = (w >> 1) * 32, wn = (w & 1) * 48;
    const int lr = lane & 15, lk = (lane >> 4) * 8;
    const int orow = (lane >> 4) * 4;

    f32x4 acc[2][3] = {};
#pragma unroll
    for (int ks = 0; ks < 192; ks += 32) {
        bf16x8 a0 = *(const bf16x8*)&As[(wm + lr) * 200 + ks + lk];
        bf16x8 a1 = *(const bf16x8*)&As[(wm + 16 + lr) * 200 + ks + lk];
#pragma unroll
        for (int ni = 0; ni < 3; ++ni) {
            bf16x8 bfr = *(const bf16x8*)&Bs[(wn + ni * 16 + lr) * 200 + ks + lk];
            acc[0][ni] = __builtin_amdgcn_mfma_f32_16x16x32_bf16(a0, bfr, acc[0][ni], 0, 0, 0);
            acc[1][ni] = __builtin_amdgcn_mfma_f32_16x16x32_bf16(a1, bfr, acc[1][ni], 0, 0, 0);
        }
    }
#pragma unroll
    for (int mi = 0; mi < 2; ++mi)
#pragma unroll
        for (int ni = 0; ni < 3; ++ni) {
#pragma unroll
            for (int r = 0; r < 4; ++r) {
                int m = m0 + wm + mi * 16 + orow + r;
                yo[(long)m * CC + wn + ni * 16 + lr] = acc[mi][ni][r];
            }
        }
}

// ---------------- depthwise causal conv (k=4) + bias + SiLU ----------------
__global__ void k_conv(const float* __restrict__ xz_x, const float* __restrict__ conv_w,
                       const float* __restrict__ conv_b, float* __restrict__ xbuf)
{
    int idx = blockIdx.x * blockDim.x + threadIdx.x;
    const int total = D_DIRS * BB * LL * PP;
    for (; idx < total; idx += gridDim.x * blockDim.x) {
        int p = idx % PP;
        int m = idx / PP;
        int t = m & (LL - 1);
        int d = m >> 13;
        float acc = conv_b[d * PP + p];
        const float* wp = conv_w + (d * PP + p) * 4;
#pragma unroll
        for (int k = 0; k < 4; ++k) {
            int tt = t - 3 + k;
            if (tt >= 0) acc += wp[k] * xz_x[(long)(m - 3 + k) * PP + p];
        }
        xbuf[(long)m * PP + p] = acc / (1.0f + __expf(-acc));
    }
}

// ---------------- scan pass 1: 1 thread per (p,chunk,db), 16 states in regs ----------------
__global__ __launch_bounds__(192) void k_pass1(
    const float* __restrict__ xbuf, const float* __restrict__ proj,
    const float* __restrict__ A_log, const float* __restrict__ W_dt,
    const float* __restrict__ b_dt,
    float2* __restrict__ cb)   // [chunk][seq] interleaved (pa, h)
{
    __shared__ __align__(16) float pl[CLEN * 40];  // 0..5 dtproj, 6..7 zero, 8..23 B, 24..39 C
    const int tid = threadIdx.x;      // = p
    const int chunk = blockIdx.x;
    const int db = blockIdx.y;
    const int d = db >> 1;
    const int m0 = db * LL + chunk * CLEN;

    const float* pr = proj + (long)m0 * NPROJ;
    for (int i = tid; i < CLEN * NPROJ; i += 192) {
        int r = i / NPROJ, c = i - r * NPROJ;
        int col = (c < 6) ? c : c + 2;
        pl[r * 40 + col] = pr[i];
    }
    if (tid < CLEN) { pl[tid * 40 + 6] = 0.f; pl[tid * 40 + 7] = 0.f; }

    const int p = tid;
    float xv[CLEN];
    const float* xp = xbuf + (long)m0 * PP + p;
#pragma unroll
    for (int s = 0; s < CLEN; ++s) xv[s] = xp[s * PP];

    float A[16];
    const float* al = A_log + (d * PP + p) * NN;
#pragma unroll
    for (int n = 0; n < 16; ++n) A[n] = -__expf(al[n]);
    float w[6];
    const float* wd = W_dt + (d * PP + p) * DTR;
#pragma unroll
    for (int r = 0; r < 6; ++r) w[r] = wd[r];
    const float bdt = b_dt[d * PP + p];
    float h[16], pa[16];
#pragma unroll
    for (int n = 0; n < 16; ++n) { h[n] = 0.f; pa[n] = 1.f; }
    __syncthreads();

#pragma unroll
    for (int s = 0; s < CLEN; ++s) {
        const float* row = pl + s * 40;
        float4 d0 = *(const float4*)(row);
        float4 d1 = *(const float4*)(row + 4);
        float v = bdt + d0.x*w[0] + d0.y*w[1] + d0.z*w[2] + d0.w*w[3] + d1.x*w[4] + d1.y*w[5];
        float dtv = fast_softplus(v);
        float dtx = dtv * xv[s];
        const float4* B4 = reinterpret_cast<const float4*>(row + 8);
#pragma unroll
        for (int q = 0; q < 4; ++q) {
            float4 Bv = B4[q];
            float dA;
            dA = __expf(dtv * A[4*q+0]); h[4*q+0] = dA*h[4*q+0] + dtx*Bv.x; pa[4*q+0] *= dA;
            dA = __expf(dtv * A[4*q+1]); h[4*q+1] = dA*h[4*q+1] + dtx*Bv.y; pa[4*q+1] *= dA;
            dA = __expf(dtv * A[4*q+2]); h[4*q+2] = dA*h[4*q+2] + dtx*Bv.z; pa[4*q+2] *= dA;
            dA = __expf(dtv * A[4*q+3]); h[4*q+3] = dA*h[4*q+3] + dtx*Bv.w; pa[4*q+3] *= dA;
        }
    }
    const int seq = db * (PP * NN) + p * NN;
    float4* co = reinterpret_cast<float4*>(cb + (long)chunk * SEQT + seq);
#pragma unroll
    for (int q = 0; q < 8; ++q)
        co[q] = make_float4(pa[2*q], h[2*q], pa[2*q+1], h[2*q+1]);
}

// ---------------- serial scan over chunks -> initial states (in .y) ----------------
__global__ void k_chunkscan(float2* __restrict__ cb)
{
    int seq = blockIdx.x * 256 + threadIdx.x;   // 0..24575
    float run = 0.0f;
    for (int c = 0; c < NCH; c += 8) {
        float2 v[8];
#pragma unroll
        for (int i = 0; i < 8; ++i) v[i] = cb[(long)(c + i) * SEQT + seq];
#pragma unroll
        for (int i = 0; i < 8; ++i) {
            reinterpret_cast<float*>(cb + (long)(c + i) * SEQT + seq)[1] = run;
            run = v[i].x * run + v[i].y;
        }
    }
}

// ---------------- scan pass 2: emit ys = (sum_n h*C + x*Dp) * silu(z) ----------------
__global__ __launch_bounds__(192) void k_pass2(
    const float* xbuf_in, const float* __restrict__ proj,
    const float* __restrict__ A_log, const float* __restrict__ W_dt,
    const float* __restrict__ b_dt, const float* __restrict__ Dp,
    const __bf16* __restrict__ zb, const float2* __restrict__ cb,
    float* ys)   // ys aliases xbuf_in: read-before-write per thread/column
{
    __shared__ __align__(16) float pl[CLEN * 40];
    const int tid = threadIdx.x;
    const int chunk = blockIdx.x;
    const int db = blockIdx.y;
    const int d = db >> 1;
    const int m0 = db * LL + chunk * CLEN;

    const float* pr = proj + (long)m0 * NPROJ;
    for (int i = tid; i < CLEN * NPROJ; i += 192) {
        int r = i / NPROJ, c = i - r * NPROJ;
        int col = (c < 6) ? c : c + 2;
        pl[r * 40 + col] = pr[i];
    }
    if (tid < CLEN) { pl[tid * 40 + 6] = 0.f; pl[tid * 40 + 7] = 0.f; }

    const int p = tid;
    float xv[CLEN], zv[CLEN];
    const float* xp = xbuf_in + (long)m0 * PP + p;
    const __bf16* zp = zb + (long)m0 * PP + p;
#pragma unroll
    for (int s = 0; s < CLEN; ++s) xv[s] = xp[s * PP];
#pragma unroll
    for (int s = 0; s < CLEN; ++s) zv[s] = (float)zp[s * PP];

    float A[16];
    const float* al = A_log + (d * PP + p) * NN;
#pragma unroll
    for (int n = 0; n < 16; ++n) A[n] = -__expf(al[n]);
    float w[6];
    const float* wd = W_dt + (d * PP + p) * DTR;
#pragma unroll
    for (int r = 0; r < 6; ++r) w[r] = wd[r];
    const float bdt = b_dt[d * PP + p];
    const float Dv = Dp[d * PP + p];

    float h[16];
    const int seq = db * (PP * NN) + p * NN;
    const float4* hi = reinterpret_cast<const float4*>(cb + (long)chunk * SEQT + seq);
#pragma unroll
    for (int q = 0; q < 8; ++q) {
        float4 hv = hi[q];
        h[2*q] = hv.y; h[2*q+1] = hv.w;
    }
    __syncthreads();

    float* yp = ys + (long)m0 * PP + p;
#pragma unroll
    for (int s = 0; s < CLEN; ++s) {
        const float* row = pl + s * 40;
        float4 d0 = *(const float4*)(row);
        float4 d1 = *(const float4*)(row + 4);
        float v = bdt + d0.x*w[0] + d0.y*w[1] + d0.z*w[2] + d0.w*w[3] + d1.x*w[4] + d1.y*w[5];
        float dtv = fast_softplus(v);
        float dtx = dtv * xv[s];
        const float4* B4 = reinterpret_cast<const float4*>(row + 8);
        const float4* C4 = reinterpret_cast<const float4*>(row + 24);
        float y = 0.0f;
#pragma unroll
        for (int q = 0; q < 4; ++q) {
            float4 Bv = B4[q];
            float4 Cv = C4[q];
            float dA;
            dA = __expf(dtv * A[4*q+0]); h[4*q+0] = dA*h[4*q+0] + dtx*Bv.x; y += h[4*q+0]*Cv.x;
            dA = __expf(dtv * A[4*q+1]); h[4*q+1] = dA*h[4*q+1] + dtx*Bv.y; y += h[4*q+1]*Cv.y;
            dA = __expf(dtv * A[4*q+2]); h[4*q+2] = dA*h[4*q+2] + dtx*Bv.z; y += h[4*q+2]*Cv.z;
            dA = __expf(dtv * A[4*q+3]); h[4*q+3] = dA*h[4*q+3] + dtx*Bv.w; y += h[4*q+3]*Cv.w;
        }
        float zvv = zv[s];
        yp[s * PP] = (y + xv[s] * Dv) * (zvv / (1.0f + __expf(-zvv)));
    }
}

// ---------------- final combine: out = x2 + sum of 4 directional outputs ----------------
__global__ void k_final(const float* __restrict__ x2, const float* __restrict__ yo,
                        float* __restrict__ out)
{
    int idx = blockIdx.x * blockDim.x + threadIdx.x;
    const int total = BB * CC * LL;
    for (; idx < total; idx += gridDim.x * blockDim.x) {
        int w = idx & 63;
        int h = (idx >> 6) & 63;
        int c = (idx >> 12) % CC;
        int b = idx / (CC * LL);
        int lh = (h << 6) | w;
        int lw = (w << 6) | h;
        long m0 = (long)(0 * BB + b) * LL + lh;
        long m1 = (long)(1 * BB + b) * LL + (LL - 1 - lh);
        long m2 = (long)(2 * BB + b) * LL + lw;
        long m3 = (long)(3 * BB + b) * LL + (LL - 1 - lw);
        out[idx] = x2[idx] + yo[m0 * CC + c] + yo[m1 * CC + c] + yo[m2 * CC + c] + yo[m3 * CC + c];
    }
}

extern "C" void kernel_launch(void* const* d_in, const int* in_sizes, int n_in,
                              void* d_out, int out_size, void* d_ws, size_t ws_size,
                              hipStream_t stream)
{
    const float* x1     = (const float*)d_in[0];
    const float* x2     = (const float*)d_in[1];
    const float* W_in   = (const float*)d_in[2];
    const float* conv_w = (const float*)d_in[3];
    const float* conv_b = (const float*)d_in[4];
    const float* W_x    = (const float*)d_in[5];
    const float* W_dt   = (const float*)d_in[6];
    const float* b_dt   = (const float*)d_in[7];
    const float* A_log  = (const float*)d_in[8];
    const float* Dp     = (const float*)d_in[9];
    const float* W_out  = (const float*)d_in[10];
    float* out = (float*)d_out;
    float* ws  = (float*)d_ws;

    // workspace layout (float offsets), total ~29.7M floats = 118.9 MB
    float*  xz_x  = ws;                          // 6,291,456
    __bf16* zb    = (__bf16*)(ws + 6291456);     // 6,291,456 bf16 = 3,145,728 f
    float*  xbuf  = ws + 9437184;                // 6,291,456  (reused in-place as ys)
    float*  proj  = ws + 15728640;               // 1,245,184
    float2* cb    = (float2*)(ws + 16973824);    // NCH*SEQT float2 = 12,582,912 f
    __bf16* wbin  = (__bf16*)(ws + 29556736);    // 159,744 bf16
    __bf16* wbx   = (__bf16*)(ws + 29636608);    // 38,400 bf16
    __bf16* wbout = (__bf16*)(ws + 29655808);    // 76,800 bf16
    float* ys = xbuf;
    float* yo = ws + 16973824;   // aliases cb (dead after k_pass2)

    k_prep<<<dim3(1074), 256, 0, stream>>>(W_in, W_x, W_out, wbin, wbx, wbout);
    k_gemm_in<<<dim3(64, 6, 8), 256, 0, stream>>>(x1, wbin, xz_x, zb);
    k_conv<<<dim3(6144), 256, 0, stream>>>(xz_x, conv_w, conv_b, xbuf);
    k_gemm_proj<<<dim3(512), 256, 0, stream>>>(xbuf, wbx, proj);
    k_pass1<<<dim3(NCH, 8), 192, 0, stream>>>(xbuf, proj, A_log, W_dt, b_dt, cb);
    k_chunkscan<<<dim3(SEQT / 256), 256, 0, stream>>>(cb);
    k_pass2<<<dim3(NCH, 8), 192, 0, stream>>>(xbuf, proj, A_log, W_dt, b_dt, Dp, zb, cb, ys);
    k_gemm_out<<<dim3(512), 256, 0, stream>>>(ys, wbout, yo);
    k_final<<<dim3(3072), 256, 0, stream>>>(x2, yo, out);
}

// Round 6
// 199.195 us; speedup vs baseline: 1.6508x; 1.1921x over previous
//
#include <hip/hip_runtime.h>

#define D_DIRS 4
#define BB 2
#define CC 96
#define LL 4096
#define PP 192
#define TWOP 384
#define NN 16
#define DTR 6
#define NPROJ 38
#define NCH 256
#define CLEN 16
#define SEQT 24576   // 16 n * 8 db * 192 p

typedef __bf16 bf16x8 __attribute__((ext_vector_type(8)));
typedef float f32x4 __attribute__((ext_vector_type(4)));

__device__ __forceinline__ float fast_softplus(float v) {
    return fmaxf(v, 0.0f) + __logf(1.0f + __expf(-fabsf(v)));
}

// time index t (within a direction's sequence) -> flat pixel offset h*64+w in x1
__device__ __forceinline__ int pixoff(int d, int t) {
    int tt = (d & 1) ? (LL - 1 - t) : t;
    if (d < 2) return tt;                      // seq_h: l = h*W + w
    return ((tt & 63) << 6) | (tt >> 6);       // seq_w: l = w*H + h -> pixel h*W+w
}

// ---------------- weight prep: fp32 -> padded bf16 images ----------------
__global__ void k_prep(const float* __restrict__ W_in, const float* __restrict__ W_x,
                       const float* __restrict__ W_out, __bf16* __restrict__ wbin,
                       __bf16* __restrict__ wbx, __bf16* __restrict__ wbout)
{
    int i = blockIdx.x * 256 + threadIdx.x;
    const int n0 = 4 * 384 * 104, n1 = 4 * 48 * 200, n2 = 4 * 96 * 200;
    if (i < n0) {
        int c = i % 104, jd = i / 104;          // jd = d*384 + j
        wbin[i] = (c < 96) ? (__bf16)W_in[jd * 96 + c] : (__bf16)0.0f;
    } else if (i < n0 + n1) {
        int k = i - n0;
        int c = k % 200, jd = k / 200;          // jd = d*48 + j
        int d = jd / 48, j = jd - d * 48;
        float v = (j < 38 && c < 192) ? W_x[(d * 38 + j) * 192 + c] : 0.0f;
        wbx[k] = (__bf16)v;
    } else if (i < n0 + n1 + n2) {
        int k = i - n0 - n1;
        int c = k % 200, jd = k / 200;          // jd = d*96 + cout
        float v = (c < 192) ? W_out[jd * 192 + c] : 0.0f;
        wbout[k] = (__bf16)v;
    }
}

// ---------------- input GEMM (MFMA): x-half -> xz_x (f32), z-half -> zb (bf16) ----------------
__global__ __launch_bounds__(256) void k_gemm_in(
    const float* __restrict__ x1, const __bf16* __restrict__ wbin,
    float* __restrict__ xz_x, __bf16* __restrict__ zb)
{
    __shared__ __align__(16) __bf16 As[64 * 104];
    __shared__ __align__(16) __bf16 Bs[64 * 104];
    const int db = blockIdx.z;
    const int d = db >> 1, b = db & 1;
    const int t0 = blockIdx.x * 64;
    const int j0 = blockIdx.y * 64;
    const int tid = threadIdx.x;

    for (int i = tid; i < 64 * 96; i += 256) {
        int t = i & 63, c = i >> 6;
        int pix = pixoff(d, t0 + t);
        As[t * 104 + c] = (__bf16)x1[(b * CC + c) * LL + pix];
    }
    {
        const uint4* bsrc = reinterpret_cast<const uint4*>(wbin + (d * 384 + j0) * 104);
        uint4* bdst = reinterpret_cast<uint4*>(Bs);
        for (int i = tid; i < 832; i += 256) bdst[i] = bsrc[i];
    }
    __syncthreads();

    const int lane = tid & 63;
    const int w = tid >> 6;
    const int wm = (w >> 1) * 32, wn = (w & 1) * 32;
    const int lr = lane & 15, lk = (lane >> 4) * 8;
    const int orow = (lane >> 4) * 4;

    f32x4 acc[2][2] = {{{0.f,0.f,0.f,0.f},{0.f,0.f,0.f,0.f}},
                       {{0.f,0.f,0.f,0.f},{0.f,0.f,0.f,0.f}}};
#pragma unroll
    for (int ks = 0; ks < 96; ks += 32) {
        bf16x8 a0 = *(const bf16x8*)&As[(wm + lr) * 104 + ks + lk];
        bf16x8 a1 = *(const bf16x8*)&As[(wm + 16 + lr) * 104 + ks + lk];
        bf16x8 b0 = *(const bf16x8*)&Bs[(wn + lr) * 104 + ks + lk];
        bf16x8 b1 = *(const bf16x8*)&Bs[(wn + 16 + lr) * 104 + ks + lk];
        acc[0][0] = __builtin_amdgcn_mfma_f32_16x16x32_bf16(a0, b0, acc[0][0], 0, 0, 0);
        acc[0][1] = __builtin_amdgcn_mfma_f32_16x16x32_bf16(a0, b1, acc[0][1], 0, 0, 0);
        acc[1][0] = __builtin_amdgcn_mfma_f32_16x16x32_bf16(a1, b0, acc[1][0], 0, 0, 0);
        acc[1][1] = __builtin_amdgcn_mfma_f32_16x16x32_bf16(a1, b1, acc[1][1], 0, 0, 0);
    }
#pragma unroll
    for (int mi = 0; mi < 2; ++mi)
#pragma unroll
        for (int ni = 0; ni < 2; ++ni) {
            int jcol = j0 + wn + ni * 16 + lr;
            long mbase = (long)(db * LL + t0 + wm + mi * 16 + orow);
            if (jcol < PP) {
#pragma unroll
                for (int r = 0; r < 4; ++r) xz_x[(mbase + r) * PP + jcol] = acc[mi][ni][r];
            } else {
#pragma unroll
                for (int r = 0; r < 4; ++r) zb[(mbase + r) * PP + jcol - PP] = (__bf16)acc[mi][ni][r];
            }
        }
}

// ---------------- proj GEMM (MFMA): proj[m][j] = sum_k xbuf[m][k]*W_x[d][j][k], J=38 ----------------
__global__ __launch_bounds__(256) void k_gemm_proj(
    const float* __restrict__ Abuf, const __bf16* __restrict__ wbx, float* __restrict__ proj)
{
    __shared__ __align__(16) __bf16 As[64 * 200];
    __shared__ __align__(16) __bf16 Bs[48 * 200];
    const int m0 = blockIdx.x * 64;
    const int d = m0 >> 13;
    const int tid = threadIdx.x;

    for (int i = tid; i < 64 * 48; i += 256) {
        int t = i / 48, c4 = (i - t * 48) * 4;
        float4 v = *(const float4*)&Abuf[(long)(m0 + t) * PP + c4];
        union { __bf16 h[4]; uint2 u; } pk;
        pk.h[0] = (__bf16)v.x; pk.h[1] = (__bf16)v.y; pk.h[2] = (__bf16)v.z; pk.h[3] = (__bf16)v.w;
        *(uint2*)&As[t * 200 + c4] = pk.u;
    }
    {
        const uint4* bsrc = reinterpret_cast<const uint4*>(wbx + d * 48 * 200);
        uint4* bdst = reinterpret_cast<uint4*>(Bs);
        for (int i = tid; i < 1200; i += 256) bdst[i] = bsrc[i];
    }
    __syncthreads();

    const int lane = tid & 63;
    const int w = tid >> 6;
    const int lr = lane & 15, lk = (lane >> 4) * 8;
    const int orow = (lane >> 4) * 4;

    f32x4 acc[3] = {{0.f,0.f,0.f,0.f},{0.f,0.f,0.f,0.f},{0.f,0.f,0.f,0.f}};
#pragma unroll
    for (int ks = 0; ks < 192; ks += 32) {
        bf16x8 a = *(const bf16x8*)&As[(w * 16 + lr) * 200 + ks + lk];
#pragma unroll
        for (int ni = 0; ni < 3; ++ni) {
            bf16x8 bfr = *(const bf16x8*)&Bs[(ni * 16 + lr) * 200 + ks + lk];
            acc[ni] = __builtin_amdgcn_mfma_f32_16x16x32_bf16(a, bfr, acc[ni], 0, 0, 0);
        }
    }
#pragma unroll
    for (int ni = 0; ni < 3; ++ni) {
        int j = ni * 16 + lr;
        if (j < NPROJ) {
#pragma unroll
            for (int r = 0; r < 4; ++r) {
                int m = m0 + w * 16 + orow + r;
                proj[(long)m * NPROJ + j] = acc[ni][r];
            }
        }
    }
}

// ---------------- out GEMM (MFMA): yo[m][c] = sum_p ys[m][p]*W_out[d][c][p], J=96 ----------------
__global__ __launch_bounds__(256) void k_gemm_out(
    const float* __restrict__ Abuf, const __bf16* __restrict__ wbout, float* __restrict__ yo)
{
    __shared__ __align__(16) __bf16 As[64 * 200];
    __shared__ __align__(16) __bf16 Bs[96 * 200];
    const int m0 = blockIdx.x * 64;
    const int d = m0 >> 13;
    const int tid = threadIdx.x;

    for (int i = tid; i < 64 * 48; i += 256) {
        int t = i / 48, c4 = (i - t * 48) * 4;
        float4 v = *(const float4*)&Abuf[(long)(m0 + t) * PP + c4];
        union { __bf16 h[4]; uint2 u; } pk;
        pk.h[0] = (__bf16)v.x; pk.h[1] = (__bf16)v.y; pk.h[2] = (__bf16)v.z; pk.h[3] = (__bf16)v.w;
        *(uint2*)&As[t * 200 + c4] = pk.u;
    }
    {
        const uint4* bsrc = reinterpret_cast<const uint4*>(wbout + d * 96 * 200);
        uint4* bdst = reinterpret_cast<uint4*>(Bs);
        for (int i = tid; i < 2400; i += 256) bdst[i] = bsrc[i];
    }
    __syncthreads();

    const int lane = tid & 63;
    const int w = tid >> 6;
    const int wm = (w >> 1) * 32, wn = (w & 1) * 48;
    const int lr = lane & 15, lk = (lane >> 4) * 8;
    const int orow = (lane >> 4) * 4;

    f32x4 acc[2][3] = {};
#pragma unroll
    for (int ks = 0; ks < 192; ks += 32) {
        bf16x8 a0 = *(const bf16x8*)&As[(wm + lr) * 200 + ks + lk];
        bf16x8 a1 = *(const bf16x8*)&As[(wm + 16 + lr) * 200 + ks + lk];
#pragma unroll
        for (int ni = 0; ni < 3; ++ni) {
            bf16x8 bfr = *(const bf16x8*)&Bs[(wn + ni * 16 + lr) * 200 + ks + lk];
            acc[0][ni] = __builtin_amdgcn_mfma_f32_16x16x32_bf16(a0, bfr, acc[0][ni], 0, 0, 0);
            acc[1][ni] = __builtin_amdgcn_mfma_f32_16x16x32_bf16(a1, bfr, acc[1][ni], 0, 0, 0);
        }
    }
#pragma unroll
    for (int mi = 0; mi < 2; ++mi)
#pragma unroll
        for (int ni = 0; ni < 3; ++ni) {
#pragma unroll
            for (int r = 0; r < 4; ++r) {
                int m = m0 + wm + mi * 16 + orow + r;
                yo[(long)m * CC + wn + ni * 16 + lr] = acc[mi][ni][r];
            }
        }
}

// ---------------- depthwise causal conv (k=4) + bias + SiLU ----------------
__global__ void k_conv(const float* __restrict__ xz_x, const float* __restrict__ conv_w,
                       const float* __restrict__ conv_b, float* __restrict__ xbuf)
{
    int idx = blockIdx.x * blockDim.x + threadIdx.x;
    const int total = D_DIRS * BB * LL * PP;
    for (; idx < total; idx += gridDim.x * blockDim.x) {
        int p = idx % PP;
        int m = idx / PP;
        int t = m & (LL - 1);
        int d = m >> 13;
        float acc = conv_b[d * PP + p];
        const float* wp = conv_w + (d * PP + p) * 4;
#pragma unroll
        for (int k = 0; k < 4; ++k) {
            int tt = t - 3 + k;
            if (tt >= 0) acc += wp[k] * xz_x[(long)(m - 3 + k) * PP + p];
        }
        xbuf[(long)m * PP + p] = acc / (1.0f + __expf(-acc));
    }
}

// ---------------- scan pass 1: 1 thread per (p,chunk,db), h[16] in regs, x from LDS ----------------
__global__ __launch_bounds__(192) void k_pass1(
    const float* __restrict__ xbuf, const float* __restrict__ proj,
    const float* __restrict__ A_log, const float* __restrict__ W_dt,
    const float* __restrict__ b_dt,
    float* __restrict__ cb_pa, float* __restrict__ cb_h)
{
    __shared__ __align__(16) float pl[CLEN * 40];  // 0..5 dtproj, 6..7 zero, 8..23 B, 24..39 C
    __shared__ __align__(16) float xs[CLEN * PP];  // staged x chunk
    const int tid = threadIdx.x;      // = p
    const int chunk = blockIdx.x;
    const int db = blockIdx.y;
    const int d = db >> 1;
    const int m0 = db * LL + chunk * CLEN;

    const float* pr = proj + (long)m0 * NPROJ;
    for (int i = tid; i < CLEN * NPROJ; i += 192) {
        int r = i / NPROJ, c = i - r * NPROJ;
        int col = (c < 6) ? c : c + 2;
        pl[r * 40 + col] = pr[i];
    }
    {
        const float4* xsrc = reinterpret_cast<const float4*>(xbuf + (long)m0 * PP);
        float4* xdst = reinterpret_cast<float4*>(xs);
#pragma unroll
        for (int i = 0; i < 4; ++i) xdst[tid + 192 * i] = xsrc[tid + 192 * i];
    }

    const int p = tid;
    float A[16];
    {
        const float4* al4 = reinterpret_cast<const float4*>(A_log + (d * PP + p) * NN);
#pragma unroll
        for (int q = 0; q < 4; ++q) {
            float4 a = al4[q];
            A[4*q]   = -__expf(a.x); A[4*q+1] = -__expf(a.y);
            A[4*q+2] = -__expf(a.z); A[4*q+3] = -__expf(a.w);
        }
    }
    float w[6];
    const float* wd = W_dt + (d * PP + p) * DTR;
#pragma unroll
    for (int r = 0; r < 6; ++r) w[r] = wd[r];
    const float bdt = b_dt[d * PP + p];
    float h[16];
#pragma unroll
    for (int n = 0; n < 16; ++n) h[n] = 0.f;
    float sdt = 0.f;
    __syncthreads();

#pragma unroll
    for (int s = 0; s < CLEN; ++s) {
        const float* row = pl + s * 40;
        float4 d0 = *(const float4*)(row);
        float4 d1 = *(const float4*)(row + 4);
        float v = bdt + d0.x*w[0] + d0.y*w[1] + d0.z*w[2] + d0.w*w[3] + d1.x*w[4] + d1.y*w[5];
        float dtv = fast_softplus(v);
        sdt += dtv;
        float dtx = dtv * xs[s * PP + p];
        const float4* B4 = reinterpret_cast<const float4*>(row + 8);
#pragma unroll
        for (int q = 0; q < 4; ++q) {
            float4 Bv = B4[q];
            h[4*q+0] = __expf(dtv * A[4*q+0])*h[4*q+0] + dtx*Bv.x;
            h[4*q+1] = __expf(dtv * A[4*q+1])*h[4*q+1] + dtx*Bv.y;
            h[4*q+2] = __expf(dtv * A[4*q+2])*h[4*q+2] + dtx*Bv.z;
            h[4*q+3] = __expf(dtv * A[4*q+3])*h[4*q+3] + dtx*Bv.w;
        }
    }
    // cb layout: [chunk][n][db*192+p] — all stores lane-coalesced
    const long cbase = (long)chunk * SEQT + db * PP + p;
#pragma unroll
    for (int n = 0; n < 16; ++n) {
        cb_pa[cbase + n * 1536] = __expf(A[n] * sdt);   // prod of dA over chunk
        cb_h [cbase + n * 1536] = h[n];
    }
}

// ---------------- serial scan over chunks -> initial states (into cb_h) ----------------
__global__ void k_chunkscan(const float* __restrict__ cb_pa, float* __restrict__ cb_h)
{
    int j = blockIdx.x * 256 + threadIdx.x;   // 0..24575 = n*1536 + db*192 + p
    float run = 0.0f;
    for (int c = 0; c < NCH; c += 8) {
        float pa[8], hh[8];
#pragma unroll
        for (int i = 0; i < 8; ++i) {
            long o = (long)(c + i) * SEQT + j;
            pa[i] = cb_pa[o]; hh[i] = cb_h[o];
        }
#pragma unroll
        for (int i = 0; i < 8; ++i) {
            cb_h[(long)(c + i) * SEQT + j] = run;
            run = pa[i] * run + hh[i];
        }
    }
}

// ---------------- scan pass 2: emit ys = (sum_n h*C + x*Dp) * silu(z) ----------------
__global__ __launch_bounds__(192) void k_pass2(
    const float* xbuf_in, const float* __restrict__ proj,
    const float* __restrict__ A_log, const float* __restrict__ W_dt,
    const float* __restrict__ b_dt, const float* __restrict__ Dp,
    const __bf16* __restrict__ zb, const float* __restrict__ cb_h,
    float* ys)   // ys aliases xbuf_in: block stages its region to LDS before any write
{
    __shared__ __align__(16) float pl[CLEN * 40];
    __shared__ __align__(16) float xs[CLEN * PP];
    __shared__ __align__(16) __bf16 zs[CLEN * PP];
    const int tid = threadIdx.x;
    const int chunk = blockIdx.x;
    const int db = blockIdx.y;
    const int d = db >> 1;
    const int m0 = db * LL + chunk * CLEN;

    const float* pr = proj + (long)m0 * NPROJ;
    for (int i = tid; i < CLEN * NPROJ; i += 192) {
        int r = i / NPROJ, c = i - r * NPROJ;
        int col = (c < 6) ? c : c + 2;
        pl[r * 40 + col] = pr[i];
    }
    {
        const float4* xsrc = reinterpret_cast<const float4*>(xbuf_in + (long)m0 * PP);
        float4* xdst = reinterpret_cast<float4*>(xs);
#pragma unroll
        for (int i = 0; i < 4; ++i) xdst[tid + 192 * i] = xsrc[tid + 192 * i];
        const uint4* zsrc = reinterpret_cast<const uint4*>(zb + (long)m0 * PP);
        uint4* zdst = reinterpret_cast<uint4*>(zs);
        zdst[tid] = zsrc[tid];
        if (tid < 192) zdst[tid + 192] = zsrc[tid + 192];
    }

    const int p = tid;
    float A[16];
    {
        const float4* al4 = reinterpret_cast<const float4*>(A_log + (d * PP + p) * NN);
#pragma unroll
        for (int q = 0; q < 4; ++q) {
            float4 a = al4[q];
            A[4*q]   = -__expf(a.x); A[4*q+1] = -__expf(a.y);
            A[4*q+2] = -__expf(a.z); A[4*q+3] = -__expf(a.w);
        }
    }
    float w[6];
    const float* wd = W_dt + (d * PP + p) * DTR;
#pragma unroll
    for (int r = 0; r < 6; ++r) w[r] = wd[r];
    const float bdt = b_dt[d * PP + p];
    const float Dv = Dp[d * PP + p];

    float h[16];
    const long cbase = (long)chunk * SEQT + db * PP + p;
#pragma unroll
    for (int n = 0; n < 16; ++n) h[n] = cb_h[cbase + n * 1536];
    __syncthreads();

    float* yp = ys + (long)m0 * PP + p;
#pragma unroll
    for (int s = 0; s < CLEN; ++s) {
        const float* row = pl + s * 40;
        float4 d0 = *(const float4*)(row);
        float4 d1 = *(const float4*)(row + 4);
        float v = bdt + d0.x*w[0] + d0.y*w[1] + d0.z*w[2] + d0.w*w[3] + d1.x*w[4] + d1.y*w[5];
        float dtv = fast_softplus(v);
        float xvv = xs[s * PP + p];
        float dtx = dtv * xvv;
        const float4* B4 = reinterpret_cast<const float4*>(row + 8);
        const float4* C4 = reinterpret_cast<const float4*>(row + 24);
        float y = 0.0f;
#pragma unroll
        for (int q = 0; q < 4; ++q) {
            float4 Bv = B4[q];
            float4 Cv = C4[q];
            h[4*q+0] = __expf(dtv * A[4*q+0])*h[4*q+0] + dtx*Bv.x; y += h[4*q+0]*Cv.x;
            h[4*q+1] = __expf(dtv * A[4*q+1])*h[4*q+1] + dtx*Bv.y; y += h[4*q+1]*Cv.y;
            h[4*q+2] = __expf(dtv * A[4*q+2])*h[4*q+2] + dtx*Bv.z; y += h[4*q+2]*Cv.z;
            h[4*q+3] = __expf(dtv * A[4*q+3])*h[4*q+3] + dtx*Bv.w; y += h[4*q+3]*Cv.w;
        }
        float zvv = (float)zs[s * PP + p];
        yp[s * PP] = (y + xvv * Dv) * (zvv / (1.0f + __expf(-zvv)));
    }
}

// ---------------- final combine: out = x2 + sum of 4 directional outputs ----------------
__global__ void k_final(const float* __restrict__ x2, const float* __restrict__ yo,
                        float* __restrict__ out)
{
    int idx = blockIdx.x * blockDim.x + threadIdx.x;
    const int total = BB * CC * LL;
    for (; idx < total; idx += gridDim.x * blockDim.x) {
        int w = idx & 63;
        int h = (idx >> 6) & 63;
        int c = (idx >> 12) % CC;
        int b = idx / (CC * LL);
        int lh = (h << 6) | w;
        int lw = (w << 6) | h;
        long m0 = (long)(0 * BB + b) * LL + lh;
        long m1 = (long)(1 * BB + b) * LL + (LL - 1 - lh);
        long m2 = (long)(2 * BB + b) * LL + lw;
        long m3 = (long)(3 * BB + b) * LL + (LL - 1 - lw);
        out[idx] = x2[idx] + yo[m0 * CC + c] + yo[m1 * CC + c] + yo[m2 * CC + c] + yo[m3 * CC + c];
    }
}

extern "C" void kernel_launch(void* const* d_in, const int* in_sizes, int n_in,
                              void* d_out, int out_size, void* d_ws, size_t ws_size,
                              hipStream_t stream)
{
    const float* x1     = (const float*)d_in[0];
    const float* x2     = (const float*)d_in[1];
    const float* W_in   = (const float*)d_in[2];
    const float* conv_w = (const float*)d_in[3];
    const float* conv_b = (const float*)d_in[4];
    const float* W_x    = (const float*)d_in[5];
    const float* W_dt   = (const float*)d_in[6];
    const float* b_dt   = (const float*)d_in[7];
    const float* A_log  = (const float*)d_in[8];
    const float* Dp     = (const float*)d_in[9];
    const float* W_out  = (const float*)d_in[10];
    float* out = (float*)d_out;
    float* ws  = (float*)d_ws;

    // workspace layout (float offsets), total ~29.7M floats = 118.9 MB
    float*  xz_x  = ws;                          // 6,291,456
    __bf16* zb    = (__bf16*)(ws + 6291456);     // 6,291,456 bf16 = 3,145,728 f
    float*  xbuf  = ws + 9437184;                // 6,291,456  (reused in-place as ys)
    float*  proj  = ws + 15728640;               // 1,245,184
    float*  cb_pa = ws + 16973824;               // 6,291,456
    float*  cb_h  = ws + 23265280;               // 6,291,456
    __bf16* wbin  = (__bf16*)(ws + 29556736);    // 159,744 bf16
    __bf16* wbx   = (__bf16*)(ws + 29636608);    // 38,400 bf16
    __bf16* wbout = (__bf16*)(ws + 29655808);    // 76,800 bf16
    float* ys = xbuf;
    float* yo = cb_pa;   // dead after k_chunkscan

    k_prep<<<dim3(1074), 256, 0, stream>>>(W_in, W_x, W_out, wbin, wbx, wbout);
    k_gemm_in<<<dim3(64, 6, 8), 256, 0, stream>>>(x1, wbin, xz_x, zb);
    k_conv<<<dim3(6144), 256, 0, stream>>>(xz_x, conv_w, conv_b, xbuf);
    k_gemm_proj<<<dim3(512), 256, 0, stream>>>(xbuf, wbx, proj);
    k_pass1<<<dim3(NCH, 8), 192, 0, stream>>>(xbuf, proj, A_log, W_dt, b_dt, cb_pa, cb_h);
    k_chunkscan<<<dim3(SEQT / 256), 256, 0, stream>>>(cb_pa, cb_h);
    k_pass2<<<dim3(NCH, 8), 192, 0, stream>>>(xbuf, proj, A_log, W_dt, b_dt, Dp, zb, cb_h, ys);
    k_gemm_out<<<dim3(512), 256, 0, stream>>>(ys, wbout, yo);
    k_final<<<dim3(3072), 256, 0, stream>>>(x2, yo, out);
}

// Round 7
// 157.423 us; speedup vs baseline: 2.0889x; 1.2653x over previous
//
#include <hip/hip_runtime.h>

#define D_DIRS 4
#define BB 2
#define CC 96
#define LL 4096
#define PP 192
#define TWOP 384
#define NN 16
#define DTR 6
#define NPROJ 38
#define NCH 256
#define CLEN 16
#define SEQT 24576   // 16 n * 8 db * 192 p

typedef __bf16 bf16x8 __attribute__((ext_vector_type(8)));
typedef float f32x4 __attribute__((ext_vector_type(4)));

__device__ __forceinline__ float fast_softplus(float v) {
    return fmaxf(v, 0.0f) + __logf(1.0f + __expf(-fabsf(v)));
}

// ---------------- weight prep: fp32 -> padded bf16 images ----------------
__global__ void k_prep(const float* __restrict__ W_in, const float* __restrict__ W_x,
                       const float* __restrict__ W_out, __bf16* __restrict__ wbin,
                       __bf16* __restrict__ wbx, __bf16* __restrict__ wbout)
{
    int i = blockIdx.x * 256 + threadIdx.x;
    const int n0 = 4 * 384 * 104, n1 = 4 * 48 * 200, n2 = 4 * 96 * 200;
    if (i < n0) {
        int c = i % 104, jd = i / 104;          // jd = d*384 + j
        wbin[i] = (c < 96) ? (__bf16)W_in[jd * 96 + c] : (__bf16)0.0f;
    } else if (i < n0 + n1) {
        int k = i - n0;
        int c = k % 200, jd = k / 200;          // jd = d*48 + j
        int d = jd / 48, j = jd - d * 48;
        float v = (j < 38 && c < 192) ? W_x[(d * 38 + j) * 192 + c] : 0.0f;
        wbx[k] = (__bf16)v;
    } else if (i < n0 + n1 + n2) {
        int k = i - n0 - n1;
        int c = k % 200, jd = k / 200;          // jd = d*96 + cout
        float v = (c < 192) ? W_out[jd * 192 + c] : 0.0f;
        wbout[k] = (__bf16)v;
    }
}

// ---------------- x1 -> bf16 images: imgH[b][h*64+w][c], imgW[b][w*64+h][c], rows padded to 104 ----------------
__global__ __launch_bounds__(256) void k_img(
    const float* __restrict__ x1, __bf16* __restrict__ imgH, __bf16* __restrict__ imgW)
{
    __shared__ float t[96 * 65];
    const int b = blockIdx.y;
    const int lt = blockIdx.x;        // h
    const int tid = threadIdx.x;
    for (int i = tid; i < 96 * 64; i += 256) {
        int c = i >> 6, lw = i & 63;
        t[c * 65 + lw] = x1[((b * 96 + c) << 12) + (lt << 6) + lw];
    }
    __syncthreads();
    for (int i = tid; i < 64 * 12; i += 256) {
        int lw = i / 12, q = i - lw * 12;
        union { __bf16 h[8]; uint4 u; } pk;
#pragma unroll
        for (int j = 0; j < 8; ++j) pk.h[j] = (__bf16)t[(q * 8 + j) * 65 + lw];
        ((uint4*)(imgH + (long)((b << 12) + (lt << 6) + lw) * 104))[q] = pk.u;
        ((uint4*)(imgW + (long)((b << 12) + (lw << 6) + lt) * 104))[q] = pk.u;
    }
}

// ---------------- input GEMM (MFMA): x-half -> xz_x (f32), z-half -> zb (bf16) ----------------
__global__ __launch_bounds__(256) void k_gemm_in(
    const __bf16* __restrict__ imgH, const __bf16* __restrict__ imgW,
    const __bf16* __restrict__ wbin, float* __restrict__ xz_x, __bf16* __restrict__ zb)
{
    __shared__ __align__(16) __bf16 As[64 * 104];
    __shared__ __align__(16) __bf16 Bs[64 * 104];
    const int db = blockIdx.y;
    const int d = db >> 1, b = db & 1;
    const int t0 = blockIdx.x * 64;
    const int tid = threadIdx.x;
    const __bf16* img = (d < 2 ? imgH : imgW) + (long)b * (LL * 104);

    {
        uint4* adst = (uint4*)As;
        for (int i = tid; i < 832; i += 256) {
            int r = i / 13, q = i - r * 13;
            int l = (d & 1) ? (LL - 1 - (t0 + r)) : (t0 + r);
            adst[i] = ((const uint4*)(img + (long)l * 104))[q];
        }
    }

    const int lane = tid & 63;
    const int w = tid >> 6;
    const int wm = (w >> 1) * 32, wn = (w & 1) * 32;
    const int lr = lane & 15, lk = (lane >> 4) * 8;
    const int orow = (lane >> 4) * 4;

    for (int j0 = 0; j0 < TWOP; j0 += 64) {
        __syncthreads();
        {
            const uint4* bsrc = (const uint4*)(wbin + (long)(d * TWOP + j0) * 104);
            uint4* bdst = (uint4*)Bs;
            for (int i = tid; i < 832; i += 256) bdst[i] = bsrc[i];
        }
        __syncthreads();

        f32x4 acc[2][2] = {{{0.f,0.f,0.f,0.f},{0.f,0.f,0.f,0.f}},
                           {{0.f,0.f,0.f,0.f},{0.f,0.f,0.f,0.f}}};
#pragma unroll
        for (int ks = 0; ks < 96; ks += 32) {
            bf16x8 a0 = *(const bf16x8*)&As[(wm + lr) * 104 + ks + lk];
            bf16x8 a1 = *(const bf16x8*)&As[(wm + 16 + lr) * 104 + ks + lk];
            bf16x8 b0 = *(const bf16x8*)&Bs[(wn + lr) * 104 + ks + lk];
            bf16x8 b1 = *(const bf16x8*)&Bs[(wn + 16 + lr) * 104 + ks + lk];
            acc[0][0] = __builtin_amdgcn_mfma_f32_16x16x32_bf16(a0, b0, acc[0][0], 0, 0, 0);
            acc[0][1] = __builtin_amdgcn_mfma_f32_16x16x32_bf16(a0, b1, acc[0][1], 0, 0, 0);
            acc[1][0] = __builtin_amdgcn_mfma_f32_16x16x32_bf16(a1, b0, acc[1][0], 0, 0, 0);
            acc[1][1] = __builtin_amdgcn_mfma_f32_16x16x32_bf16(a1, b1, acc[1][1], 0, 0, 0);
        }
#pragma unroll
        for (int mi = 0; mi < 2; ++mi)
#pragma unroll
            for (int ni = 0; ni < 2; ++ni) {
                long mbase = (long)(db * LL + t0 + wm + mi * 16 + orow);
                int jcol = j0 + wn + ni * 16 + lr;
                if (j0 < PP) {
#pragma unroll
                    for (int r = 0; r < 4; ++r) xz_x[(mbase + r) * PP + jcol] = acc[mi][ni][r];
                } else {
#pragma unroll
                    for (int r = 0; r < 4; ++r) zb[(mbase + r) * PP + jcol - PP] = (__bf16)acc[mi][ni][r];
                }
            }
    }
}

// ---------------- depthwise causal conv + bias + SiLU -> padded bf16 image [m][200] ----------------
__global__ __launch_bounds__(192) void k_conv(
    const float* __restrict__ xz_x, const float* __restrict__ conv_w,
    const float* __restrict__ conv_b, __bf16* __restrict__ xb16)
{
    __shared__ float xs[67 * 192];
    const int db = blockIdx.y;
    const int t0 = blockIdx.x * 64;
    const int d = db >> 1;
    const int m0 = db * LL + t0;
    const int tid = threadIdx.x;

    const float4* src = (const float4*)(xz_x + ((long)m0 - 3) * PP);
    for (int i = tid; i < 67 * 48; i += 192) {
        float4 v;
        if (t0 == 0 && i < 144) v = make_float4(0.f, 0.f, 0.f, 0.f);
        else v = src[i];
        ((float4*)xs)[i] = v;
    }

    const int p = tid;
    const float* wp = conv_w + (d * PP + p) * 4;
    float w0 = wp[0], w1 = wp[1], w2 = wp[2], w3 = wp[3];
    float bias = conv_b[d * PP + p];
    __syncthreads();

    for (int t = 0; t < 64; ++t) {
        float acc = bias + w0 * xs[t * PP + p] + w1 * xs[(t + 1) * PP + p]
                         + w2 * xs[(t + 2) * PP + p] + w3 * xs[(t + 3) * PP + p];
        float s = acc / (1.0f + __expf(-acc));
        xb16[(long)(m0 + t) * 200 + p] = (__bf16)s;
    }
}

// ---------------- proj GEMM (MFMA): proj[m][j] = sum_k xb16[m][k]*W_x[d][j][k], J=38 ----------------
__global__ __launch_bounds__(256) void k_gemm_proj(
    const __bf16* __restrict__ xb16, const __bf16* __restrict__ wbx, float* __restrict__ proj)
{
    __shared__ __align__(16) __bf16 As[64 * 200];
    __shared__ __align__(16) __bf16 Bs[48 * 200];
    const int m0 = blockIdx.x * 64;
    const int d = m0 >> 13;
    const int tid = threadIdx.x;

    for (int i = tid; i < 1600; i += 256) {
        int r = i / 25, q = i - r * 25;
        ((uint4*)As)[i] = ((const uint4*)(xb16 + (long)(m0 + r) * 200))[q];
    }
    {
        const uint4* bsrc = (const uint4*)(wbx + (long)d * 48 * 200);
        uint4* bdst = (uint4*)Bs;
        for (int i = tid; i < 1200; i += 256) bdst[i] = bsrc[i];
    }
    __syncthreads();

    const int lane = tid & 63;
    const int w = tid >> 6;
    const int lr = lane & 15, lk = (lane >> 4) * 8;
    const int orow = (lane >> 4) * 4;

    f32x4 acc[3] = {{0.f,0.f,0.f,0.f},{0.f,0.f,0.f,0.f},{0.f,0.f,0.f,0.f}};
#pragma unroll
    for (int ks = 0; ks < 192; ks += 32) {
        bf16x8 a = *(const bf16x8*)&As[(w * 16 + lr) * 200 + ks + lk];
#pragma unroll
        for (int ni = 0; ni < 3; ++ni) {
            bf16x8 bfr = *(const bf16x8*)&Bs[(ni * 16 + lr) * 200 + ks + lk];
            acc[ni] = __builtin_amdgcn_mfma_f32_16x16x32_bf16(a, bfr, acc[ni], 0, 0, 0);
        }
    }
#pragma unroll
    for (int ni = 0; ni < 3; ++ni) {
        int j = ni * 16 + lr;
        if (j < NPROJ) {
#pragma unroll
            for (int r = 0; r < 4; ++r) {
                int m = m0 + w * 16 + orow + r;
                proj[(long)m * NPROJ + j] = acc[ni][r];
            }
        }
    }
}

// ---------------- out GEMM (MFMA): yo[m][c] = sum_p ysb[m][p]*W_out[d][c][p], J=96 ----------------
__global__ __launch_bounds__(256) void k_gemm_out(
    const __bf16* __restrict__ ysb, const __bf16* __restrict__ wbout, float* __restrict__ yo)
{
    __shared__ __align__(16) __bf16 As[64 * 200];
    __shared__ __align__(16) __bf16 Bs[96 * 200];
    const int m0 = blockIdx.x * 64;
    const int d = m0 >> 13;
    const int tid = threadIdx.x;

    for (int i = tid; i < 1600; i += 256) {
        int r = i / 25, q = i - r * 25;
        ((uint4*)As)[i] = ((const uint4*)(ysb + (long)(m0 + r) * 200))[q];
    }
    {
        const uint4* bsrc = (const uint4*)(wbout + (long)d * 96 * 200);
        uint4* bdst = (uint4*)Bs;
        for (int i = tid; i < 2400; i += 256) bdst[i] = bsrc[i];
    }
    __syncthreads();

    const int lane = tid & 63;
    const int w = tid >> 6;
    const int wm = (w >> 1) * 32, wn = (w & 1) * 48;
    const int lr = lane & 15, lk = (lane >> 4) * 8;
    const int orow = (lane >> 4) * 4;

    f32x4 acc[2][3] = {};
#pragma unroll
    for (int ks = 0; ks < 192; ks += 32) {
        bf16x8 a0 = *(const bf16x8*)&As[(wm + lr) * 200 + ks + lk];
        bf16x8 a1 = *(const bf16x8*)&As[(wm + 16 + lr) * 200 + ks + lk];
#pragma unroll
        for (int ni = 0; ni < 3; ++ni) {
            bf16x8 bfr = *(const bf16x8*)&Bs[(wn + ni * 16 + lr) * 200 + ks + lk];
            acc[0][ni] = __builtin_amdgcn_mfma_f32_16x16x32_bf16(a0, bfr, acc[0][ni], 0, 0, 0);
            acc[1][ni] = __builtin_amdgcn_mfma_f32_16x16x32_bf16(a1, bfr, acc[1][ni], 0, 0, 0);
        }
    }
#pragma unroll
    for (int mi = 0; mi < 2; ++mi)
#pragma unroll
        for (int ni = 0; ni < 3; ++ni) {
#pragma unroll
            for (int r = 0; r < 4; ++r) {
                int m = m0 + wm + mi * 16 + orow + r;
                yo[(long)m * CC + wn + ni * 16 + lr] = acc[mi][ni][r];
            }
        }
}

// ---------------- scan pass 1 ----------------
__global__ __launch_bounds__(192) void k_pass1(
    const __bf16* __restrict__ xb16, const float* __restrict__ proj,
    const float* __restrict__ A_log, const float* __restrict__ W_dt,
    const float* __restrict__ b_dt,
    float* __restrict__ cb_pa, float* __restrict__ cb_h)
{
    __shared__ __align__(16) float pl[CLEN * 40];   // 0..5 dtproj, 8..23 B, 24..39 C
    __shared__ __align__(16) __bf16 xsb[CLEN * 200];
    const int tid = threadIdx.x;      // = p
    const int chunk = blockIdx.x;
    const int db = blockIdx.y;
    const int d = db >> 1;
    const int m0 = db * LL + chunk * CLEN;

    const float* pr = proj + (long)m0 * NPROJ;
    for (int i = tid; i < CLEN * NPROJ; i += 192) {
        int r = i / NPROJ, c = i - r * NPROJ;
        int col = (c < 6) ? c : c + 2;
        pl[r * 40 + col] = pr[i];
    }
    for (int i = tid; i < 400; i += 192) {
        int r = i / 25, q = i - r * 25;
        ((uint4*)xsb)[i] = ((const uint4*)(xb16 + (long)(m0 + r) * 200))[q];
    }

    const int p = tid;
    float A[16];
    {
        const float4* al4 = reinterpret_cast<const float4*>(A_log + (d * PP + p) * NN);
#pragma unroll
        for (int q = 0; q < 4; ++q) {
            float4 a = al4[q];
            A[4*q]   = -__expf(a.x); A[4*q+1] = -__expf(a.y);
            A[4*q+2] = -__expf(a.z); A[4*q+3] = -__expf(a.w);
        }
    }
    float w[6];
    const float* wd = W_dt + (d * PP + p) * DTR;
#pragma unroll
    for (int r = 0; r < 6; ++r) w[r] = wd[r];
    const float bdt = b_dt[d * PP + p];
    float h[16];
#pragma unroll
    for (int n = 0; n < 16; ++n) h[n] = 0.f;
    float sdt = 0.f;
    __syncthreads();

#pragma unroll
    for (int s = 0; s < CLEN; ++s) {
        const float* row = pl + s * 40;
        float4 d0 = *(const float4*)(row);
        float4 d1 = *(const float4*)(row + 4);
        float v = bdt + d0.x*w[0] + d0.y*w[1] + d0.z*w[2] + d0.w*w[3] + d1.x*w[4] + d1.y*w[5];
        float dtv = fast_softplus(v);
        sdt += dtv;
        float dtx = dtv * (float)xsb[s * 200 + p];
        const float4* B4 = reinterpret_cast<const float4*>(row + 8);
#pragma unroll
        for (int q = 0; q < 4; ++q) {
            float4 Bv = B4[q];
            h[4*q+0] = __expf(dtv * A[4*q+0])*h[4*q+0] + dtx*Bv.x;
            h[4*q+1] = __expf(dtv * A[4*q+1])*h[4*q+1] + dtx*Bv.y;
            h[4*q+2] = __expf(dtv * A[4*q+2])*h[4*q+2] + dtx*Bv.z;
            h[4*q+3] = __expf(dtv * A[4*q+3])*h[4*q+3] + dtx*Bv.w;
        }
    }
    const long cbase = (long)chunk * SEQT + db * PP + p;
#pragma unroll
    for (int n = 0; n < 16; ++n) {
        cb_pa[cbase + n * 1536] = __expf(A[n] * sdt);
        cb_h [cbase + n * 1536] = h[n];
    }
}

// ---------------- serial scan over chunks -> initial states ----------------
__global__ void k_chunkscan(const float* __restrict__ cb_pa, float* __restrict__ cb_h)
{
    int j = blockIdx.x * 256 + threadIdx.x;
    float run = 0.0f;
    for (int c = 0; c < NCH; c += 8) {
        float pa[8], hh[8];
#pragma unroll
        for (int i = 0; i < 8; ++i) {
            long o = (long)(c + i) * SEQT + j;
            pa[i] = cb_pa[o]; hh[i] = cb_h[o];
        }
#pragma unroll
        for (int i = 0; i < 8; ++i) {
            cb_h[(long)(c + i) * SEQT + j] = run;
            run = pa[i] * run + hh[i];
        }
    }
}

// ---------------- scan pass 2: ysb = (sum_n h*C + x*Dp) * silu(z), bf16 padded [m][200] ----------------
__global__ __launch_bounds__(192) void k_pass2(
    const __bf16* __restrict__ xb16, const float* __restrict__ proj,
    const float* __restrict__ A_log, const float* __restrict__ W_dt,
    const float* __restrict__ b_dt, const float* __restrict__ Dp,
    const __bf16* __restrict__ zb, const float* __restrict__ cb_h,
    __bf16* __restrict__ ysb)
{
    __shared__ __align__(16) float pl[CLEN * 40];
    __shared__ __align__(16) __bf16 xsb[CLEN * 200];
    __shared__ __align__(16) __bf16 zs[CLEN * PP];
    const int tid = threadIdx.x;
    const int chunk = blockIdx.x;
    const int db = blockIdx.y;
    const int d = db >> 1;
    const int m0 = db * LL + chunk * CLEN;

    const float* pr = proj + (long)m0 * NPROJ;
    for (int i = tid; i < CLEN * NPROJ; i += 192) {
        int r = i / NPROJ, c = i - r * NPROJ;
        int col = (c < 6) ? c : c + 2;
        pl[r * 40 + col] = pr[i];
    }
    for (int i = tid; i < 400; i += 192) {
        int r = i / 25, q = i - r * 25;
        ((uint4*)xsb)[i] = ((const uint4*)(xb16 + (long)(m0 + r) * 200))[q];
    }
    {
        const uint4* zsrc = reinterpret_cast<const uint4*>(zb + (long)m0 * PP);
        uint4* zdst = reinterpret_cast<uint4*>(zs);
        zdst[tid] = zsrc[tid];
        zdst[tid + 192] = zsrc[tid + 192];
    }

    const int p = tid;
    float A[16];
    {
        const float4* al4 = reinterpret_cast<const float4*>(A_log + (d * PP + p) * NN);
#pragma unroll
        for (int q = 0; q < 4; ++q) {
            float4 a = al4[q];
            A[4*q]   = -__expf(a.x); A[4*q+1] = -__expf(a.y);
            A[4*q+2] = -__expf(a.z); A[4*q+3] = -__expf(a.w);
        }
    }
    float w[6];
    const float* wd = W_dt + (d * PP + p) * DTR;
#pragma unroll
    for (int r = 0; r < 6; ++r) w[r] = wd[r];
    const float bdt = b_dt[d * PP + p];
    const float Dv = Dp[d * PP + p];

    float h[16];
    const long cbase = (long)chunk * SEQT + db * PP + p;
#pragma unroll
    for (int n = 0; n < 16; ++n) h[n] = cb_h[cbase + n * 1536];
    __syncthreads();

#pragma unroll
    for (int s = 0; s < CLEN; ++s) {
        const float* row = pl + s * 40;
        float4 d0 = *(const float4*)(row);
        float4 d1 = *(const float4*)(row + 4);
        float v = bdt + d0.x*w[0] + d0.y*w[1] + d0.z*w[2] + d0.w*w[3] + d1.x*w[4] + d1.y*w[5];
        float dtv = fast_softplus(v);
        float xvv = (float)xsb[s * 200 + p];
        float dtx = dtv * xvv;
        const float4* B4 = reinterpret_cast<const float4*>(row + 8);
        const float4* C4 = reinterpret_cast<const float4*>(row + 24);
        float y = 0.0f;
#pragma unroll
        for (int q = 0; q < 4; ++q) {
            float4 Bv = B4[q];
            float4 Cv = C4[q];
            h[4*q+0] = __expf(dtv * A[4*q+0])*h[4*q+0] + dtx*Bv.x; y += h[4*q+0]*Cv.x;
            h[4*q+1] = __expf(dtv * A[4*q+1])*h[4*q+1] + dtx*Bv.y; y += h[4*q+1]*Cv.y;
            h[4*q+2] = __expf(dtv * A[4*q+2])*h[4*q+2] + dtx*Bv.z; y += h[4*q+2]*Cv.z;
            h[4*q+3] = __expf(dtv * A[4*q+3])*h[4*q+3] + dtx*Bv.w; y += h[4*q+3]*Cv.w;
        }
        float zvv = (float)zs[s * PP + p];
        ysb[(long)(m0 + s) * 200 + p] = (__bf16)((y + xvv * Dv) * (zvv / (1.0f + __expf(-zvv))));
    }
}

// ---------------- final combine ----------------
__global__ void k_final(const float* __restrict__ x2, const float* __restrict__ yo,
                        float* __restrict__ out)
{
    int idx = blockIdx.x * blockDim.x + threadIdx.x;
    const int total = BB * CC * LL;
    for (; idx < total; idx += gridDim.x * blockDim.x) {
        int w = idx & 63;
        int h = (idx >> 6) & 63;
        int c = (idx >> 12) % CC;
        int b = idx / (CC * LL);
        int lh = (h << 6) | w;
        int lw = (w << 6) | h;
        long m0 = (long)(0 * BB + b) * LL + lh;
        long m1 = (long)(1 * BB + b) * LL + (LL - 1 - lh);
        long m2 = (long)(2 * BB + b) * LL + lw;
        long m3 = (long)(3 * BB + b) * LL + (LL - 1 - lw);
        out[idx] = x2[idx] + yo[m0 * CC + c] + yo[m1 * CC + c] + yo[m2 * CC + c] + yo[m3 * CC + c];
    }
}

extern "C" void kernel_launch(void* const* d_in, const int* in_sizes, int n_in,
                              void* d_out, int out_size, void* d_ws, size_t ws_size,
                              hipStream_t stream)
{
    const float* x1     = (const float*)d_in[0];
    const float* x2     = (const float*)d_in[1];
    const float* W_in   = (const float*)d_in[2];
    const float* conv_w = (const float*)d_in[3];
    const float* conv_b = (const float*)d_in[4];
    const float* W_x    = (const float*)d_in[5];
    const float* W_dt   = (const float*)d_in[6];
    const float* b_dt   = (const float*)d_in[7];
    const float* A_log  = (const float*)d_in[8];
    const float* Dp     = (const float*)d_in[9];
    const float* W_out  = (const float*)d_in[10];
    float* out = (float*)d_out;
    float* ws  = (float*)d_ws;

    // workspace (float offsets), total ~27.53M f = 110.1 MB
    float*  xz_x  = ws;                          // 6,291,456  (ysb aliases after conv)
    __bf16* zb    = (__bf16*)(ws + 6291456);     // 3,145,728 f
    __bf16* xb16  = (__bf16*)(ws + 9437184);     // 32768*200 bf16 = 3,276,800 f
    float*  proj  = ws + 12713984;               // 1,245,184
    float*  cb_pa = ws + 13959168;               // 6,291,456  (yo aliases after chunkscan)
    float*  cb_h  = ws + 20250624;               // 6,291,456
    __bf16* imgH  = (__bf16*)(ws + 26542080);    // 851,968 bf16 = 425,984 f
    __bf16* imgW  = (__bf16*)(ws + 26968064);    // 425,984 f
    __bf16* wbin  = (__bf16*)(ws + 27394048);    // 79,872 f
    __bf16* wbx   = (__bf16*)(ws + 27473920);    // 19,200 f
    __bf16* wbout = (__bf16*)(ws + 27493120);    // 38,400 f
    __bf16* ysb = (__bf16*)xz_x;   // xz_x dead after k_conv
    float*  yo  = cb_pa;           // cb_pa dead after k_chunkscan

    k_prep<<<dim3(1074), 256, 0, stream>>>(W_in, W_x, W_out, wbin, wbx, wbout);
    k_img<<<dim3(64, 2), 256, 0, stream>>>(x1, imgH, imgW);
    k_gemm_in<<<dim3(64, 8), 256, 0, stream>>>(imgH, imgW, wbin, xz_x, zb);
    k_conv<<<dim3(64, 8), 192, 0, stream>>>(xz_x, conv_w, conv_b, xb16);
    k_gemm_proj<<<dim3(512), 256, 0, stream>>>(xb16, wbx, proj);
    k_pass1<<<dim3(NCH, 8), 192, 0, stream>>>(xb16, proj, A_log, W_dt, b_dt, cb_pa, cb_h);
    k_chunkscan<<<dim3(SEQT / 256), 256, 0, stream>>>(cb_pa, cb_h);
    k_pass2<<<dim3(NCH, 8), 192, 0, stream>>>(xb16, proj, A_log, W_dt, b_dt, Dp, zb, cb_h, ysb);
    k_gemm_out<<<dim3(512), 256, 0, stream>>>(ysb, wbout, yo);
    k_final<<<dim3(3072), 256, 0, stream>>>(x2, yo, out);
}